// Round 3
// baseline (279.960 us; speedup 1.0000x reference)
//
#include <hip/hip_runtime.h>

typedef __attribute__((ext_vector_type(8))) short bf16x8;
typedef __attribute__((ext_vector_type(4))) float f32x4;
typedef __attribute__((ext_vector_type(8))) unsigned short ushort8;
typedef __attribute__((ext_vector_type(4))) unsigned short ushort4_t;

#define LSEQ 2048
#define NB 2
#define EMB 1024
#define NHEAD 16
#define HD 64

__device__ __forceinline__ unsigned short f2bf(float f) {
  unsigned u = __builtin_bit_cast(unsigned, f);
  u += 0x7fffu + ((u >> 16) & 1u);   // RNE (finite inputs only)
  return (unsigned short)(u >> 16);
}
__device__ __forceinline__ float bf2f(unsigned short s) {
  return __builtin_bit_cast(float, ((unsigned)s) << 16);
}

// async global->LDS, 16B per lane. LDS dest = wave-uniform base + lane*16.
__device__ __forceinline__ void gll16(const void* g, void* l) {
  __builtin_amdgcn_global_load_lds((const __attribute__((address_space(1))) unsigned*)g,
                                   (__attribute__((address_space(3))) unsigned*)l, 16, 0, 0);
}

// fp32 -> bf16 convert, vectorized float4 -> 4x bf16
__global__ __launch_bounds__(256) void cvt_f32_bf16(const float* __restrict__ in,
                                                    unsigned short* __restrict__ out, int n4) {
  int i = blockIdx.x * 256 + threadIdx.x;
  if (i >= n4) return;
  float4 v = ((const float4*)in)[i];
  ushort4_t o;
  o.x = f2bf(v.x); o.y = f2bf(v.y); o.z = f2bf(v.z); o.w = f2bf(v.w);
  ((ushort4_t*)out)[i] = o;
}

// C[M][Ncol] = A[M][K] * B[Ncol][K]^T + bias[col]   (NT GEMM, both K-contiguous)
// 128x128 tile, BK=64, 4 waves (2x2), each wave 64x64 = 4x4 frags of 16x16x32 bf16 MFMA.
template <bool OUT_BF16>
__global__ __launch_bounds__(256, 2) void gemm_bf16_nt(
    const unsigned short* __restrict__ A, const unsigned short* __restrict__ B,
    const float* __restrict__ bias, void* __restrict__ Cout, int M, int Ncol, int K) {
  __shared__ unsigned short Asm[128 * 64];
  __shared__ unsigned short Bsm[128 * 64];
  const int tid = threadIdx.x;
  const int wave = tid >> 6, lane = tid & 63;
  const int wr = (wave >> 1) * 64, wc = (wave & 1) * 64;
  const int lr = lane & 15, lg = lane >> 4;
  const int bm = blockIdx.x * 128, bn = blockIdx.y * 128;

  f32x4 acc[4][4];
#pragma unroll
  for (int i = 0; i < 4; ++i)
#pragma unroll
    for (int j = 0; j < 4; ++j) acc[i][j] = (f32x4){0.f, 0.f, 0.f, 0.f};

  for (int kt = 0; kt < K; kt += 64) {
    // stage A,B tiles: 128 rows x 64 k (128B rows), linear LDS, 16B/lane chunks
#pragma unroll
    for (int c = 0; c < 4; ++c) {
      int idx = (c * 4 + wave) * 64 + lane;
      int row = idx >> 3, ch = (idx & 7) * 8;
      gll16(A + (size_t)(bm + row) * K + kt + ch, &Asm[(c * 4 + wave) * 512]);
      gll16(B + (size_t)(bn + row) * K + kt + ch, &Bsm[(c * 4 + wave) * 512]);
    }
    __syncthreads();
#pragma unroll
    for (int ks = 0; ks < 2; ++ks) {
      bf16x8 af[4], bfr[4];
#pragma unroll
      for (int i = 0; i < 4; ++i)
        af[i] = *(const bf16x8*)&Asm[(wr + i * 16 + lr) * 64 + ks * 32 + lg * 8];
#pragma unroll
      for (int j = 0; j < 4; ++j)
        bfr[j] = *(const bf16x8*)&Bsm[(wc + j * 16 + lr) * 64 + ks * 32 + lg * 8];
#pragma unroll
      for (int i = 0; i < 4; ++i)
#pragma unroll
        for (int j = 0; j < 4; ++j)
          acc[i][j] = __builtin_amdgcn_mfma_f32_16x16x32_bf16(af[i], bfr[j], acc[i][j], 0, 0, 0);
    }
    __syncthreads();
  }
  // epilogue: C/D layout col=lane&15, row=(lane>>4)*4+reg
#pragma unroll
  for (int i = 0; i < 4; ++i) {
#pragma unroll
    for (int j = 0; j < 4; ++j) {
      int col = bn + wc + j * 16 + lr;
      float bv = bias[col];
#pragma unroll
      for (int r = 0; r < 4; ++r) {
        int row = bm + wr + i * 16 + lg * 4 + r;
        float v = acc[i][j][r] + bv;
        if constexpr (OUT_BF16)
          ((unsigned short*)Cout)[(size_t)row * Ncol + col] = f2bf(v);
        else
          ((float*)Cout)[(size_t)row * Ncol + col] = v;
      }
    }
  }
}

// V^T producer: vt[nh][d][l] (bf16) from qkv rows, 64x64 tiles through LDS
__global__ __launch_bounds__(256) void transpose_v(const unsigned short* __restrict__ qkv,
                                                   unsigned short* __restrict__ vt) {
  __shared__ unsigned short t[64][72];
  const int nh = blockIdx.y, n = nh >> 4, h = nh & 15;
  const int lt = blockIdx.x * 64;
  const int tid = threadIdx.x;
#pragma unroll
  for (int it = 0; it < 2; ++it) {
    int idx = it * 256 + tid;
    int l = idx >> 3, ch = (idx & 7) * 8;
    ushort8 v = *(const ushort8*)(qkv + (size_t)((lt + l) * NB + n) * 3072 + 2 * EMB + h * HD + ch);
    *(ushort8*)&t[l][ch] = v;
  }
  __syncthreads();
  int d = tid >> 2, lc = (tid & 3) * 16;
  unsigned short tmp[16];
#pragma unroll
  for (int i = 0; i < 16; ++i) tmp[i] = t[lc + i][d];
#pragma unroll
  for (int i = 0; i < 2; ++i)
    *(ushort8*)(vt + (size_t)(nh * HD + d) * LSEQ + lt + lc + i * 8) = *(const ushort8*)&tmp[i * 8];
}

// Flash attention: block = (q-tile of 64 rows) x (n,h). 4 waves x 16 q-rows.
// Double-buffered K/V tiles via global_load_lds (stage t+1 before computing t,
// one barrier per tile). LDS XOR-swizzled via pre-swizzled global source.
// Softmax in exp2 domain (log2e folded into Q scale). XCD-chunked block remap.
__global__ __launch_bounds__(256, 3) void flash_attn(const unsigned short* __restrict__ qkv,
                                                     const unsigned short* __restrict__ vt,
                                                     unsigned short* __restrict__ ob) {
  __shared__ unsigned short Ksm[2][64 * 64];
  __shared__ unsigned short Vsm[2][64 * 64];   // [d][key]
  __shared__ unsigned short Psm[4][16 * 72];
  const int tid = threadIdx.x, wave = tid >> 6, lane = tid & 63;
  const int lr = lane & 15, lg = lane >> 4;
  // bijective XCD-chunked remap: 1024 blocks = 8 XCDs x 128
  const int flat = blockIdx.y * 32 + blockIdx.x;
  const int fb = (flat & 7) * 128 + (flat >> 3);
  const int nh = fb >> 5, qt = fb & 31;
  const int n = nh >> 4, h = nh & 15;
  const int q0 = qt * 64 + wave * 16;

  // staging swizzle: lane stages LDS chunk (lane&7) of row (base + lane>>3);
  // source global chunk = (lane&7) ^ (row&7).
  const int sch = ((lane & 7) ^ ((lane >> 3) & 7)) * 8;
  const unsigned short* Kbase = qkv + (size_t)n * 3072 + EMB + h * HD + sch;  // + key*6144
  const unsigned short* Vbase = vt + (size_t)nh * HD * LSEQ + sch;            // + d*2048 + key0

  // Q fragments, pre-scaled by 0.125*log2(e) for exp2-domain softmax
  bf16x8 qf[2];
  {
    const unsigned short* qb = qkv + (size_t)((q0 + lr) * NB + n) * 3072 + h * HD + lg * 8;
#pragma unroll
    for (int ks = 0; ks < 2; ++ks) {
      bf16x8 tv = *(const bf16x8*)(qb + ks * 32);
#pragma unroll
      for (int e = 0; e < 8; ++e)
        tv[e] = (short)f2bf(bf2f((unsigned short)tv[e]) * 0.18033688f);
      qf[ks] = tv;
    }
  }

  auto stage = [&](int buf, int kt) {
#pragma unroll
    for (int c = 0; c < 2; ++c) {
      int row = ((c * 4 + wave) * 64 + lane) >> 3;
      gll16(Kbase + (size_t)(kt * 64 + row) * (NB * 3072), &Ksm[buf][(c * 4 + wave) * 512]);
      gll16(Vbase + (size_t)row * LSEQ + kt * 64, &Vsm[buf][(c * 4 + wave) * 512]);
    }
  };

  float m[4], lsum[4];
  f32x4 o[4];
#pragma unroll
  for (int r = 0; r < 4; ++r) { m[r] = -1e30f; lsum[r] = 0.f; }
#pragma unroll
  for (int d = 0; d < 4; ++d) o[d] = (f32x4){0.f, 0.f, 0.f, 0.f};

  stage(0, 0);
  __syncthreads();   // drains vmcnt(0) + barrier
  int cur = 0;

  for (int kt = 0; kt < LSEQ / 64; ++kt) {
    if (kt < LSEQ / 64 - 1) stage(cur ^ 1, kt + 1);   // issue next tile early (hidden under compute)

    // S = (Q*scale*log2e) K^T : rows=q, cols=key  (swizzled K read)
    f32x4 s[4];
#pragma unroll
    for (int j = 0; j < 4; ++j) s[j] = (f32x4){0.f, 0.f, 0.f, 0.f};
    __builtin_amdgcn_s_setprio(1);
#pragma unroll
    for (int ks = 0; ks < 2; ++ks) {
#pragma unroll
      for (int j = 0; j < 4; ++j) {
        bf16x8 kf = *(const bf16x8*)&Ksm[cur][(j * 16 + lr) * 64 + ((ks * 4 + lg) ^ (lr & 7)) * 8];
        s[j] = __builtin_amdgcn_mfma_f32_16x16x32_bf16(qf[ks], kf, s[j], 0, 0, 0);
      }
    }
    __builtin_amdgcn_s_setprio(0);

    // online softmax, exp2 domain (per q-row; rows live as reg r within group lg)
    float mx[4];
#pragma unroll
    for (int r = 0; r < 4; ++r)
      mx[r] = fmaxf(fmaxf(s[0][r], s[1][r]), fmaxf(s[2][r], s[3][r]));
#pragma unroll
    for (int off = 1; off < 16; off <<= 1)
#pragma unroll
      for (int r = 0; r < 4; ++r) mx[r] = fmaxf(mx[r], __shfl_xor(mx[r], off));
    float al[4];
#pragma unroll
    for (int r = 0; r < 4; ++r) {
      float mn = fmaxf(m[r], mx[r]);
      al[r] = exp2f(m[r] - mn);
      m[r] = mn;
    }
    float ps[4] = {0.f, 0.f, 0.f, 0.f};
#pragma unroll
    for (int j = 0; j < 4; ++j)
#pragma unroll
      for (int r = 0; r < 4; ++r) {
        float p = exp2f(s[j][r] - m[r]);
        s[j][r] = p;
        ps[r] += p;
      }
#pragma unroll
    for (int off = 1; off < 16; off <<= 1)
#pragma unroll
      for (int r = 0; r < 4; ++r) ps[r] += __shfl_xor(ps[r], off);
#pragma unroll
    for (int r = 0; r < 4; ++r) lsum[r] = lsum[r] * al[r] + ps[r];
#pragma unroll
    for (int d = 0; d < 4; ++d)
#pragma unroll
      for (int r = 0; r < 4; ++r) o[d][r] *= al[r];

    // P -> per-wave LDS (bf16), then PV (swizzled V read)
#pragma unroll
    for (int j = 0; j < 4; ++j)
#pragma unroll
      for (int r = 0; r < 4; ++r)
        Psm[wave][(lg * 4 + r) * 72 + j * 16 + lr] = f2bf(s[j][r]);
    __builtin_amdgcn_s_setprio(1);
#pragma unroll
    for (int ks = 0; ks < 2; ++ks) {
      bf16x8 pf = *(const bf16x8*)&Psm[wave][lr * 72 + ks * 32 + lg * 8];
#pragma unroll
      for (int d = 0; d < 4; ++d) {
        bf16x8 vf = *(const bf16x8*)&Vsm[cur][(d * 16 + lr) * 64 + ((ks * 4 + lg) ^ (lr & 7)) * 8];
        o[d] = __builtin_amdgcn_mfma_f32_16x16x32_bf16(pf, vf, o[d], 0, 0, 0);
      }
    }
    __builtin_amdgcn_s_setprio(0);

    __syncthreads();   // drains next tile's loads + protects buffer swap
    cur ^= 1;
  }

  // normalize + write O rows as bf16 (row q, col h*64+d)
#pragma unroll
  for (int r = 0; r < 4; ++r) {
    float inv = 1.0f / lsum[r];
    int q = q0 + lg * 4 + r;
#pragma unroll
    for (int d = 0; d < 4; ++d)
      ob[(size_t)(q * NB + n) * EMB + h * HD + d * 16 + lr] = f2bf(o[d][r] * inv);
  }
}

extern "C" void kernel_launch(void* const* d_in, const int* in_sizes, int n_in,
                              void* d_out, int out_size, void* d_ws, size_t ws_size,
                              hipStream_t stream) {
  const float* x = (const float*)d_in[0];
  const float* wqkv = (const float*)d_in[1];
  const float* bqkv = (const float*)d_in[2];
  const float* wout = (const float*)d_in[3];
  const float* bout = (const float*)d_in[4];

  char* ws = (char*)d_ws;
  unsigned short* xb    = (unsigned short*)(ws);              //  8 MB: x bf16 [4096][1024]
  unsigned short* wqkvb = (unsigned short*)(ws + 8388608);    //  6 MB: Wqkv bf16 [3072][1024]
  unsigned short* woutb = (unsigned short*)(ws + 14680064);   //  2 MB: Wout bf16 [1024][1024]
  unsigned short* qkvb  = (unsigned short*)(ws + 16777216);   // 24 MB: qkv bf16 [4096][3072]
  unsigned short* vtb   = (unsigned short*)(ws + 41943040);   //  8 MB: V^T bf16 [32][64][2048]
  unsigned short* obuf  = (unsigned short*)(ws + 50331648);   //  8 MB: attn out bf16 [4096][1024]

  cvt_f32_bf16<<<4096, 256, 0, stream>>>(x, xb, 1048576);
  cvt_f32_bf16<<<3072, 256, 0, stream>>>(wqkv, wqkvb, 786432);
  cvt_f32_bf16<<<1024, 256, 0, stream>>>(wout, woutb, 262144);

  dim3 g1(32, 24);
  gemm_bf16_nt<true><<<g1, 256, 0, stream>>>(xb, wqkvb, bqkv, qkvb, 4096, 3072, 1024);

  dim3 g2(32, 32);
  transpose_v<<<g2, 256, 0, stream>>>(qkvb, vtb);
  flash_attn<<<g2, 256, 0, stream>>>(qkvb, vtb, obuf);

  dim3 g3(32, 8);
  gemm_bf16_nt<false><<<g3, 256, 0, stream>>>(obuf, woutb, bout, d_out, 4096, 1024, 1024);
}

// Round 4
// 223.722 us; speedup vs baseline: 1.2514x; 1.2514x over previous
//
#include <hip/hip_runtime.h>

typedef __attribute__((ext_vector_type(8))) short bf16x8;
typedef __attribute__((ext_vector_type(4))) float f32x4;
typedef __attribute__((ext_vector_type(16))) float f32x16;
typedef __attribute__((ext_vector_type(8))) unsigned short ushort8;
typedef __attribute__((ext_vector_type(4))) unsigned short ushort4_t;
typedef __attribute__((ext_vector_type(4))) unsigned uint4_t;

#define LSEQ 2048
#define NB 2
#define EMB 1024
#define NHEAD 16
#define HD 64

__device__ __forceinline__ unsigned short f2bf(float f) {
  unsigned u = __builtin_bit_cast(unsigned, f);
  u += 0x7fffu + ((u >> 16) & 1u);   // RNE (finite inputs only)
  return (unsigned short)(u >> 16);
}
__device__ __forceinline__ float bf2f(unsigned short s) {
  return __builtin_bit_cast(float, ((unsigned)s) << 16);
}

// async global->LDS, 16B per lane. LDS dest = wave-uniform base + lane*16.
__device__ __forceinline__ void gll16(const void* g, void* l) {
  __builtin_amdgcn_global_load_lds((const __attribute__((address_space(1))) unsigned*)g,
                                   (__attribute__((address_space(3))) unsigned*)l, 16, 0, 0);
}

// fp32 -> bf16 convert, vectorized float4 -> 4x bf16
__global__ __launch_bounds__(256) void cvt_f32_bf16(const float* __restrict__ in,
                                                    unsigned short* __restrict__ out, int n4) {
  int i = blockIdx.x * 256 + threadIdx.x;
  if (i >= n4) return;
  float4 v = ((const float4*)in)[i];
  ushort4_t o;
  o.x = f2bf(v.x); o.y = f2bf(v.y); o.z = f2bf(v.z); o.w = f2bf(v.w);
  ((ushort4_t*)out)[i] = o;
}

// C[M][Ncol] = A[M][K] * B[Ncol][K]^T + bias[col]   (NT GEMM, both K-contiguous)
template <bool OUT_BF16>
__global__ __launch_bounds__(256, 2) void gemm_bf16_nt(
    const unsigned short* __restrict__ A, const unsigned short* __restrict__ B,
    const float* __restrict__ bias, void* __restrict__ Cout, int M, int Ncol, int K) {
  __shared__ unsigned short Asm[128 * 64];
  __shared__ unsigned short Bsm[128 * 64];
  const int tid = threadIdx.x;
  const int wave = tid >> 6, lane = tid & 63;
  const int wr = (wave >> 1) * 64, wc = (wave & 1) * 64;
  const int lr = lane & 15, lg = lane >> 4;
  const int bm = blockIdx.x * 128, bn = blockIdx.y * 128;

  f32x4 acc[4][4];
#pragma unroll
  for (int i = 0; i < 4; ++i)
#pragma unroll
    for (int j = 0; j < 4; ++j) acc[i][j] = (f32x4){0.f, 0.f, 0.f, 0.f};

  for (int kt = 0; kt < K; kt += 64) {
#pragma unroll
    for (int c = 0; c < 4; ++c) {
      int idx = (c * 4 + wave) * 64 + lane;
      int row = idx >> 3, ch = (idx & 7) * 8;
      gll16(A + (size_t)(bm + row) * K + kt + ch, &Asm[(c * 4 + wave) * 512]);
      gll16(B + (size_t)(bn + row) * K + kt + ch, &Bsm[(c * 4 + wave) * 512]);
    }
    __syncthreads();
#pragma unroll
    for (int ks = 0; ks < 2; ++ks) {
      bf16x8 af[4], bfr[4];
#pragma unroll
      for (int i = 0; i < 4; ++i)
        af[i] = *(const bf16x8*)&Asm[(wr + i * 16 + lr) * 64 + ks * 32 + lg * 8];
#pragma unroll
      for (int j = 0; j < 4; ++j)
        bfr[j] = *(const bf16x8*)&Bsm[(wc + j * 16 + lr) * 64 + ks * 32 + lg * 8];
#pragma unroll
      for (int i = 0; i < 4; ++i)
#pragma unroll
        for (int j = 0; j < 4; ++j)
          acc[i][j] = __builtin_amdgcn_mfma_f32_16x16x32_bf16(af[i], bfr[j], acc[i][j], 0, 0, 0);
    }
    __syncthreads();
  }
#pragma unroll
  for (int i = 0; i < 4; ++i) {
#pragma unroll
    for (int j = 0; j < 4; ++j) {
      int col = bn + wc + j * 16 + lr;
      float bv = bias[col];
#pragma unroll
      for (int r = 0; r < 4; ++r) {
        int row = bm + wr + i * 16 + lg * 4 + r;
        float v = acc[i][j][r] + bv;
        if constexpr (OUT_BF16)
          ((unsigned short*)Cout)[(size_t)row * Ncol + col] = f2bf(v);
        else
          ((float*)Cout)[(size_t)row * Ncol + col] = v;
      }
    }
  }
}

// V^T producer: vt[nh][d][l] (bf16) from qkv rows, 64x64 tiles through LDS
__global__ __launch_bounds__(256) void transpose_v(const unsigned short* __restrict__ qkv,
                                                   unsigned short* __restrict__ vt) {
  __shared__ unsigned short t[64][72];
  const int nh = blockIdx.y, n = nh >> 4, h = nh & 15;
  const int lt = blockIdx.x * 64;
  const int tid = threadIdx.x;
#pragma unroll
  for (int it = 0; it < 2; ++it) {
    int idx = it * 256 + tid;
    int l = idx >> 3, ch = (idx & 7) * 8;
    ushort8 v = *(const ushort8*)(qkv + (size_t)((lt + l) * NB + n) * 3072 + 2 * EMB + h * HD + ch);
    *(ushort8*)&t[l][ch] = v;
  }
  __syncthreads();
  int d = tid >> 2, lc = (tid & 3) * 16;
  unsigned short tmp[16];
#pragma unroll
  for (int i = 0; i < 16; ++i) tmp[i] = t[lc + i][d];
#pragma unroll
  for (int i = 0; i < 2; ++i)
    *(ushort8*)(vt + (size_t)(nh * HD + d) * LSEQ + lt + lc + i * 8) = *(const ushort8*)&tmp[i * 8];
}

// Flash attention, m214-style swapped layout. Block = 128 q-rows x (n,h);
// 4 waves x 32 q-rows. 32x32x16 MFMA. S^T = mfma(K, Q): lane holds 32 keys
// for ONE q (col=lane&31) -> softmax is 31 in-lane ops + one shfl_xor(32).
// P->bf16 PV fragments via v_cvt_pk_bf16_f32 + v_permlane32_swap_b32 (T12).
// PV: O^T = mfma(V^T, P). K/V double-buffered via global_load_lds, 1 barrier
// per tile; XOR-swizzled LDS via pre-swizzled global source (rule #21).
__global__ __launch_bounds__(256, 3) void flash_attn(const unsigned short* __restrict__ qkv,
                                                     const unsigned short* __restrict__ vt,
                                                     unsigned short* __restrict__ ob) {
  __shared__ unsigned short Ksm[2][64 * 64];   // [key][d]
  __shared__ unsigned short Vsm[2][64 * 64];   // [d][key]
  const int tid = threadIdx.x, wave = tid >> 6, lane = tid & 63;
  const int l31 = lane & 31, lh = lane >> 5;
  // bijective XCD-chunked remap: 512 blocks = 8 XCDs x 64
  const int flat = blockIdx.y * 16 + blockIdx.x;
  const int fb = (flat & 7) * 64 + (flat >> 3);
  const int nh = fb >> 4, qt = fb & 15;
  const int n = nh >> 4, hh = nh & 15;
  const int q = qt * 128 + wave * 32 + l31;

  // staging swizzle: LDS[row][c] holds global chunk c ^ (row&7)
  const int sch = ((lane & 7) ^ ((lane >> 3) & 7)) * 8;
  const unsigned short* Kbase = qkv + (size_t)n * 3072 + EMB + hh * HD + sch;  // + key*6144
  const unsigned short* Vbase = vt + (size_t)nh * HD * LSEQ + sch;             // + d*2048 + key0

  // Q fragments (B operand): qf[t] = Q[q][t*16 + lh*8 + j], pre-scaled 0.125*log2e
  bf16x8 qf[4];
  {
    const unsigned short* qb = qkv + ((size_t)q * NB + n) * 3072 + hh * HD + lh * 8;
#pragma unroll
    for (int t = 0; t < 4; ++t) {
      bf16x8 tv = *(const bf16x8*)(qb + t * 16);
#pragma unroll
      for (int e = 0; e < 8; ++e)
        tv[e] = (short)f2bf(bf2f((unsigned short)tv[e]) * 0.18033688f);
      qf[t] = tv;
    }
  }

  auto stage = [&](int buf, int kt) {
#pragma unroll
    for (int c = 0; c < 2; ++c) {
      int row = ((c * 4 + wave) * 64 + lane) >> 3;
      gll16(Kbase + (size_t)(kt * 64 + row) * (NB * 3072), &Ksm[buf][(c * 4 + wave) * 512]);
      gll16(Vbase + (size_t)row * LSEQ + kt * 64, &Vsm[buf][(c * 4 + wave) * 512]);
    }
  };

  float m = -1e30f, lsum = 0.f;
  f32x16 o0, o1;
#pragma unroll
  for (int r = 0; r < 16; ++r) { o0[r] = 0.f; o1[r] = 0.f; }

  stage(0, 0);
  __syncthreads();
  int cur = 0;
  const int swz = l31 & 7;

  for (int kt = 0; kt < LSEQ / 64; ++kt) {
    if (kt < LSEQ / 64 - 1) stage(cur ^ 1, kt + 1);

    // S^T[key][q] = K . Q^T  (A = K rows, B = Q cols); s0 keys 0-31, s1 keys 32-63
    f32x16 s0, s1;
#pragma unroll
    for (int r = 0; r < 16; ++r) { s0[r] = 0.f; s1[r] = 0.f; }
    __builtin_amdgcn_s_setprio(1);
#pragma unroll
    for (int t = 0; t < 4; ++t) {
      int ch = ((t * 2 + lh) ^ swz) * 8;
      bf16x8 k0 = *(const bf16x8*)&Ksm[cur][l31 * 64 + ch];
      bf16x8 k1 = *(const bf16x8*)&Ksm[cur][(32 + l31) * 64 + ch];
      s0 = __builtin_amdgcn_mfma_f32_32x32x16_bf16(k0, qf[t], s0, 0, 0, 0);
      s1 = __builtin_amdgcn_mfma_f32_32x32x16_bf16(k1, qf[t], s1, 0, 0, 0);
    }
    __builtin_amdgcn_s_setprio(0);

    // online softmax, exp2 domain. Lane owns 32 of 64 keys for q=l31; lane^32 has rest.
    float mx = fmaxf(s0[0], s1[0]);
#pragma unroll
    for (int r = 1; r < 16; ++r) mx = fmaxf(mx, fmaxf(s0[r], s1[r]));
    mx = fmaxf(mx, __shfl_xor(mx, 32));
    float mn = fmaxf(m, mx);
    float al = exp2f(m - mn);
    m = mn;
    float ps = 0.f;
#pragma unroll
    for (int r = 0; r < 16; ++r) {
      float p0 = exp2f(s0[r] - mn), p1 = exp2f(s1[r] - mn);
      s0[r] = p0; s1[r] = p1;
      ps += p0 + p1;
    }
    ps += __shfl_xor(ps, 32);
    lsum = lsum * al + ps;
#pragma unroll
    for (int r = 0; r < 16; ++r) { o0[r] *= al; o1[r] *= al; }

    // P^T fragments for PV B-operand (T12): key layout per lane is
    // key = (r&3) + 8*(r>>2) + 4*lh; pair w(2k,2k+1) with w(2k+8,2k+9) and
    // permlane32_swap -> words of keys (g*16 + lh*8 + j).
    bf16x8 pf[4];
#pragma unroll
    for (int g = 0; g < 4; ++g) {
      const int b = (g & 1) * 8;
      float a0 = (g < 2) ? s0[b + 0] : s1[b + 0];
      float a1 = (g < 2) ? s0[b + 1] : s1[b + 1];
      float a2 = (g < 2) ? s0[b + 2] : s1[b + 2];
      float a3 = (g < 2) ? s0[b + 3] : s1[b + 3];
      float a4 = (g < 2) ? s0[b + 4] : s1[b + 4];
      float a5 = (g < 2) ? s0[b + 5] : s1[b + 5];
      float a6 = (g < 2) ? s0[b + 6] : s1[b + 6];
      float a7 = (g < 2) ? s0[b + 7] : s1[b + 7];
      unsigned w0, w1, w2, w3;
      asm("v_cvt_pk_bf16_f32 %0, %1, %2" : "=v"(w0) : "v"(a0), "v"(a1));
      asm("v_cvt_pk_bf16_f32 %0, %1, %2" : "=v"(w1) : "v"(a2), "v"(a3));
      asm("v_cvt_pk_bf16_f32 %0, %1, %2" : "=v"(w2) : "v"(a4), "v"(a5));
      asm("v_cvt_pk_bf16_f32 %0, %1, %2" : "=v"(w3) : "v"(a6), "v"(a7));
      asm("v_permlane32_swap_b32 %0, %1" : "+v"(w0), "+v"(w2));
      asm("v_permlane32_swap_b32 %0, %1" : "+v"(w1), "+v"(w3));
      pf[g] = __builtin_bit_cast(bf16x8, (uint4_t){w0, w1, w2, w3});
    }

    // O^T[d][q] += V^T . P^T  (A = V^T rows=d, B = P^T cols=q)
    __builtin_amdgcn_s_setprio(1);
#pragma unroll
    for (int u = 0; u < 4; ++u) {
      int ch = ((u * 2 + lh) ^ swz) * 8;
      bf16x8 a0 = *(const bf16x8*)&Vsm[cur][l31 * 64 + ch];
      bf16x8 a1 = *(const bf16x8*)&Vsm[cur][(32 + l31) * 64 + ch];
      o0 = __builtin_amdgcn_mfma_f32_32x32x16_bf16(a0, pf[u], o0, 0, 0, 0);
      o1 = __builtin_amdgcn_mfma_f32_32x32x16_bf16(a1, pf[u], o1, 0, 0, 0);
    }
    __builtin_amdgcn_s_setprio(0);

    __syncthreads();
    cur ^= 1;
  }

  // write O rows: lane has O^T[d][q] for q=l31, d = (r&3)+8*(r>>2)+4*lh (+32 for o1)
  float inv = 1.0f / lsum;
  unsigned short* op = ob + ((size_t)q * NB + n) * EMB + hh * HD;
#pragma unroll
  for (int g = 0; g < 4; ++g) {
    ushort4_t pk0, pk1;
#pragma unroll
    for (int e = 0; e < 4; ++e) {
      pk0[e] = f2bf(o0[g * 4 + e] * inv);
      pk1[e] = f2bf(o1[g * 4 + e] * inv);
    }
    *(ushort4_t*)(op + g * 8 + lh * 4) = pk0;
    *(ushort4_t*)(op + 32 + g * 8 + lh * 4) = pk1;
  }
}

extern "C" void kernel_launch(void* const* d_in, const int* in_sizes, int n_in,
                              void* d_out, int out_size, void* d_ws, size_t ws_size,
                              hipStream_t stream) {
  const float* x = (const float*)d_in[0];
  const float* wqkv = (const float*)d_in[1];
  const float* bqkv = (const float*)d_in[2];
  const float* wout = (const float*)d_in[3];
  const float* bout = (const float*)d_in[4];

  char* ws = (char*)d_ws;
  unsigned short* xb    = (unsigned short*)(ws);              //  8 MB: x bf16 [4096][1024]
  unsigned short* wqkvb = (unsigned short*)(ws + 8388608);    //  6 MB: Wqkv bf16 [3072][1024]
  unsigned short* woutb = (unsigned short*)(ws + 14680064);   //  2 MB: Wout bf16 [1024][1024]
  unsigned short* qkvb  = (unsigned short*)(ws + 16777216);   // 24 MB: qkv bf16 [4096][3072]
  unsigned short* vtb   = (unsigned short*)(ws + 41943040);   //  8 MB: V^T bf16 [32][64][2048]
  unsigned short* obuf  = (unsigned short*)(ws + 50331648);   //  8 MB: attn out bf16 [4096][1024]

  cvt_f32_bf16<<<4096, 256, 0, stream>>>(x, xb, 1048576);
  cvt_f32_bf16<<<3072, 256, 0, stream>>>(wqkv, wqkvb, 786432);
  cvt_f32_bf16<<<1024, 256, 0, stream>>>(wout, woutb, 262144);

  dim3 g1(32, 24);
  gemm_bf16_nt<true><<<g1, 256, 0, stream>>>(xb, wqkvb, bqkv, qkvb, 4096, 3072, 1024);

  dim3 gt(32, 32);
  transpose_v<<<gt, 256, 0, stream>>>(qkvb, vtb);

  dim3 g2(16, 32);
  flash_attn<<<g2, 256, 0, stream>>>(qkvb, vtb, obuf);

  dim3 g3(32, 8);
  gemm_bf16_nt<false><<<g3, 256, 0, stream>>>(obuf, woutb, bout, d_out, 4096, 1024, 1024);
}

// Round 6
// 211.536 us; speedup vs baseline: 1.3235x; 1.0576x over previous
//
#include <hip/hip_runtime.h>

typedef __attribute__((ext_vector_type(8))) short bf16x8;
typedef __attribute__((ext_vector_type(4))) float f32x4;
typedef __attribute__((ext_vector_type(16))) float f32x16;
typedef __attribute__((ext_vector_type(8))) unsigned short ushort8;
typedef __attribute__((ext_vector_type(4))) unsigned short ushort4_t;
typedef __attribute__((ext_vector_type(4))) unsigned uint4_t;

#define LSEQ 2048
#define NB 2
#define EMB 1024
#define NHEAD 16
#define HD 64

__device__ __forceinline__ unsigned short f2bf(float f) {
  unsigned u = __builtin_bit_cast(unsigned, f);
  u += 0x7fffu + ((u >> 16) & 1u);   // RNE (finite inputs only)
  return (unsigned short)(u >> 16);
}
__device__ __forceinline__ float bf2f(unsigned short s) {
  return __builtin_bit_cast(float, ((unsigned)s) << 16);
}
__device__ __forceinline__ float vmax3(float a, float b, float c) {
  float d;
  asm("v_max3_f32 %0, %1, %2, %3" : "=v"(d) : "v"(a), "v"(b), "v"(c));
  return d;
}

// async global->LDS, 16B per lane. LDS dest = wave-uniform base + lane*16.
__device__ __forceinline__ void gll16(const void* g, void* l) {
  __builtin_amdgcn_global_load_lds((const __attribute__((address_space(1))) unsigned*)g,
                                   (__attribute__((address_space(3))) unsigned*)l, 16, 0, 0);
}

// fused fp32 -> bf16 convert for all three tensors (one launch, fewer graph bubbles)
__global__ __launch_bounds__(256) void cvt_all(const float* __restrict__ x,
                                               const float* __restrict__ wq,
                                               const float* __restrict__ wo,
                                               unsigned short* __restrict__ xb,
                                               unsigned short* __restrict__ wqb,
                                               unsigned short* __restrict__ wob) {
  int i = blockIdx.x * 256 + threadIdx.x;   // 0 .. 2097151 float4 chunks
  const float* src;
  unsigned short* dst;
  int off;
  if (i < 1048576) { src = x;  dst = xb;  off = i; }
  else if (i < 1835008) { src = wq; dst = wqb; off = i - 1048576; }
  else { src = wo; dst = wob; off = i - 1835008; }
  float4 v = ((const float4*)src)[off];
  ushort4_t o;
  o.x = f2bf(v.x); o.y = f2bf(v.y); o.z = f2bf(v.z); o.w = f2bf(v.w);
  ((ushort4_t*)dst)[off] = o;
}

// C[M][Ncol] = A[M][K] * B[Ncol][K]^T + bias[col]   (NT GEMM, both K-contiguous)
template <bool OUT_BF16>
__global__ __launch_bounds__(256, 2) void gemm_bf16_nt(
    const unsigned short* __restrict__ A, const unsigned short* __restrict__ B,
    const float* __restrict__ bias, void* __restrict__ Cout, int M, int Ncol, int K) {
  __shared__ unsigned short Asm[128 * 64];
  __shared__ unsigned short Bsm[128 * 64];
  const int tid = threadIdx.x;
  const int wave = tid >> 6, lane = tid & 63;
  const int wr = (wave >> 1) * 64, wc = (wave & 1) * 64;
  const int lr = lane & 15, lg = lane >> 4;
  const int bm = blockIdx.x * 128, bn = blockIdx.y * 128;

  f32x4 acc[4][4];
#pragma unroll
  for (int i = 0; i < 4; ++i)
#pragma unroll
    for (int j = 0; j < 4; ++j) acc[i][j] = (f32x4){0.f, 0.f, 0.f, 0.f};

  for (int kt = 0; kt < K; kt += 64) {
#pragma unroll
    for (int c = 0; c < 4; ++c) {
      int idx = (c * 4 + wave) * 64 + lane;
      int row = idx >> 3, ch = (idx & 7) * 8;
      gll16(A + (size_t)(bm + row) * K + kt + ch, &Asm[(c * 4 + wave) * 512]);
      gll16(B + (size_t)(bn + row) * K + kt + ch, &Bsm[(c * 4 + wave) * 512]);
    }
    __syncthreads();
#pragma unroll
    for (int ks = 0; ks < 2; ++ks) {
      bf16x8 af[4], bfr[4];
#pragma unroll
      for (int i = 0; i < 4; ++i)
        af[i] = *(const bf16x8*)&Asm[(wr + i * 16 + lr) * 64 + ks * 32 + lg * 8];
#pragma unroll
      for (int j = 0; j < 4; ++j)
        bfr[j] = *(const bf16x8*)&Bsm[(wc + j * 16 + lr) * 64 + ks * 32 + lg * 8];
#pragma unroll
      for (int i = 0; i < 4; ++i)
#pragma unroll
        for (int j = 0; j < 4; ++j)
          acc[i][j] = __builtin_amdgcn_mfma_f32_16x16x32_bf16(af[i], bfr[j], acc[i][j], 0, 0, 0);
    }
    __syncthreads();
  }
#pragma unroll
  for (int i = 0; i < 4; ++i) {
#pragma unroll
    for (int j = 0; j < 4; ++j) {
      int col = bn + wc + j * 16 + lr;
      float bv = bias[col];
#pragma unroll
      for (int r = 0; r < 4; ++r) {
        int row = bm + wr + i * 16 + lg * 4 + r;
        float v = acc[i][j][r] + bv;
        if constexpr (OUT_BF16)
          ((unsigned short*)Cout)[(size_t)row * Ncol + col] = f2bf(v);
        else
          ((float*)Cout)[(size_t)row * Ncol + col] = v;
      }
    }
  }
}

// V^T producer: vt[nh][d][l] (bf16) from qkv rows, 64x64 tiles through LDS
__global__ __launch_bounds__(256) void transpose_v(const unsigned short* __restrict__ qkv,
                                                   unsigned short* __restrict__ vt) {
  __shared__ unsigned short t[64][72];
  const int nh = blockIdx.y, n = nh >> 4, h = nh & 15;
  const int lt = blockIdx.x * 64;
  const int tid = threadIdx.x;
#pragma unroll
  for (int it = 0; it < 2; ++it) {
    int idx = it * 256 + tid;
    int l = idx >> 3, ch = (idx & 7) * 8;
    ushort8 v = *(const ushort8*)(qkv + (size_t)((lt + l) * NB + n) * 3072 + 2 * EMB + h * HD + ch);
    *(ushort8*)&t[l][ch] = v;
  }
  __syncthreads();
  int d = tid >> 2, lc = (tid & 3) * 16;
  unsigned short tmp[16];
#pragma unroll
  for (int i = 0; i < 16; ++i) tmp[i] = t[lc + i][d];
#pragma unroll
  for (int i = 0; i < 2; ++i)
    *(ushort8*)(vt + (size_t)(nh * HD + d) * LSEQ + lt + lc + i * 8) = *(const ushort8*)&tmp[i * 8];
}

// Flash attention, swapped layout, KVBLK=128. Block = 128 q x (n,h); 4 waves
// x 32 q. S^T = mfma(K, Q) 32x32x16: lane holds 64 of 128 keys for ONE q
// (col=lane&31; lane^32 has the rest). Defer-max (T13, THR=8 exp2-domain),
// v_max3 tree reduce, multi-accumulator sums. P->bf16 via v_cvt_pk_bf16_f32 +
// v_permlane32_swap (T12). PV: O^T = mfma(V^T, P). K/V double-buffered via
// global_load_lds (1 barrier/tile); XOR-swizzled LDS via pre-swizzled source.
__global__ __launch_bounds__(256, 2) void flash_attn(const unsigned short* __restrict__ qkv,
                                                     const unsigned short* __restrict__ vt,
                                                     unsigned short* __restrict__ ob) {
  __shared__ unsigned short Ksm[2][128 * 64];   // [key][d] rows 128B
  __shared__ unsigned short Vsm[2][64 * 128];   // [d][key] rows 256B
  const int tid = threadIdx.x, wave = tid >> 6, lane = tid & 63;
  const int l31 = lane & 31, lh = lane >> 5;
  // bijective XCD-chunked remap: 512 blocks = 8 XCDs x 64
  const int flat = blockIdx.y * 16 + blockIdx.x;
  const int fb = (flat & 7) * 64 + (flat >> 3);
  const int nh = fb >> 4, qt = fb & 15;
  const int n = nh >> 4, hh = nh & 15;
  const int q = qt * 128 + wave * 32 + l31;

  // K staging swizzle (8 chunks/row): source chunk = (lane&7) ^ (row&7), row&7 = (lane>>3)&7
  const int sch = ((lane & 7) ^ ((lane >> 3) & 7)) * 8;
  const unsigned short* Kbase = qkv + (size_t)n * 3072 + EMB + hh * HD + sch;  // + key*6144
  const size_t vbase = (size_t)nh * HD * LSEQ;

  // Q fragments (B operand): qf[t][e] = Q[q][t*16 + lh*8 + e], scaled 0.125*log2e
  bf16x8 qf[4];
  {
    const unsigned short* qb = qkv + ((size_t)q * NB + n) * 3072 + hh * HD + lh * 8;
#pragma unroll
    for (int t = 0; t < 4; ++t) {
      bf16x8 tv = *(const bf16x8*)(qb + t * 16);
#pragma unroll
      for (int e = 0; e < 8; ++e)
        tv[e] = (short)f2bf(bf2f((unsigned short)tv[e]) * 0.18033688f);
      qf[t] = tv;
    }
  }

  auto stage = [&](int buf, int kt) {
#pragma unroll
    for (int c = 0; c < 4; ++c) {
      int cc = c * 4 + wave;                 // 0..15
      int krow = cc * 8 + (lane >> 3);       // 0..127
      gll16(Kbase + (size_t)(kt * 128 + krow) * (NB * 3072), &Ksm[buf][cc * 512]);
      int vrow = cc * 4 + (lane >> 4);       // 0..63  (16 chunks/row of 256B)
      int schv = ((lane & 15) ^ ((cc & 1) * 4 + (lane >> 4))) * 8;
      gll16(vt + vbase + (size_t)vrow * LSEQ + kt * 128 + schv, &Vsm[buf][cc * 512]);
    }
  };

  float m = -1e30f, lsum = 0.f;
  f32x16 o0, o1;
#pragma unroll
  for (int r = 0; r < 16; ++r) { o0[r] = 0.f; o1[r] = 0.f; }

  stage(0, 0);
  __syncthreads();
  int cur = 0;
  const int swz = l31 & 7;

  for (int kt = 0; kt < LSEQ / 128; ++kt) {
    if (kt < LSEQ / 128 - 1) stage(cur ^ 1, kt + 1);

    // S^T[key][q]: s[kb] covers key rows kb*32..kb*32+31
    f32x16 s[4];
#pragma unroll
    for (int kb = 0; kb < 4; ++kb)
#pragma unroll
      for (int r = 0; r < 16; ++r) s[kb][r] = 0.f;
    __builtin_amdgcn_s_setprio(1);
#pragma unroll
    for (int t = 0; t < 4; ++t) {
      int ch = ((t * 2 + lh) ^ swz) * 8;
#pragma unroll
      for (int kb = 0; kb < 4; ++kb) {
        bf16x8 kf = *(const bf16x8*)&Ksm[cur][(kb * 32 + l31) * 64 + ch];
        s[kb] = __builtin_amdgcn_mfma_f32_32x32x16_bf16(kf, qf[t], s[kb], 0, 0, 0);
      }
    }
    __builtin_amdgcn_s_setprio(0);

    // tile max via v_max3 tree (per lane over its 64 keys), then lane^32 merge
    f32x16 mv;
#pragma unroll
    for (int r = 0; r < 16; ++r) mv[r] = vmax3(s[0][r], s[1][r], s[2][r]);
#pragma unroll
    for (int r = 0; r < 16; ++r) mv[r] = fmaxf(mv[r], s[3][r]);
    float t0 = vmax3(mv[0], mv[1], mv[2]);
    float t1 = vmax3(mv[3], mv[4], mv[5]);
    float t2 = vmax3(mv[6], mv[7], mv[8]);
    float t3 = vmax3(mv[9], mv[10], mv[11]);
    float t4 = vmax3(mv[12], mv[13], mv[14]);
    float mx = fmaxf(vmax3(t0, t1, t2), vmax3(t3, t4, mv[15]));
    mx = fmaxf(mx, __shfl_xor(mx, 32));

    // defer-max (T13): rescale only if some q grew past THR=8 (P <= 2^8)
    if (!__all(mx - m <= 8.0f)) {
      float mn = fmaxf(m, mx);
      float al = exp2f(m - mn);
      lsum *= al;
#pragma unroll
      for (int r = 0; r < 16; ++r) { o0[r] *= al; o1[r] *= al; }
      m = mn;
    }

    // P = exp2(S - m), sum with 4 independent accumulators
    float ps0 = 0.f, ps1 = 0.f, ps2 = 0.f, ps3 = 0.f;
#pragma unroll
    for (int kb = 0; kb < 4; ++kb) {
#pragma unroll
      for (int r = 0; r < 16; r += 4) {
        float p0 = exp2f(s[kb][r] - m);
        float p1 = exp2f(s[kb][r + 1] - m);
        float p2 = exp2f(s[kb][r + 2] - m);
        float p3 = exp2f(s[kb][r + 3] - m);
        s[kb][r] = p0; s[kb][r + 1] = p1; s[kb][r + 2] = p2; s[kb][r + 3] = p3;
        ps0 += p0; ps1 += p1; ps2 += p2; ps3 += p3;
      }
    }
    float ps = (ps0 + ps1) + (ps2 + ps3);
    ps += __shfl_xor(ps, 32);
    lsum += ps;

    // P^T fragments (T12): groups 0-3 from s[0],s[1] (keys 0-63), 4-7 from s[2],s[3]
    bf16x8 pf[8];
#pragma unroll
    for (int half = 0; half < 2; ++half) {
      const f32x16& sa = s[half * 2];
      const f32x16& sb = s[half * 2 + 1];
#pragma unroll
      for (int g = 0; g < 4; ++g) {
        const int b = (g & 1) * 8;
        float a0 = (g < 2) ? sa[b + 0] : sb[b + 0];
        float a1 = (g < 2) ? sa[b + 1] : sb[b + 1];
        float a2 = (g < 2) ? sa[b + 2] : sb[b + 2];
        float a3 = (g < 2) ? sa[b + 3] : sb[b + 3];
        float a4 = (g < 2) ? sa[b + 4] : sb[b + 4];
        float a5 = (g < 2) ? sa[b + 5] : sb[b + 5];
        float a6 = (g < 2) ? sa[b + 6] : sb[b + 6];
        float a7 = (g < 2) ? sa[b + 7] : sb[b + 7];
        unsigned w0, w1, w2, w3;
        asm("v_cvt_pk_bf16_f32 %0, %1, %2" : "=v"(w0) : "v"(a0), "v"(a1));
        asm("v_cvt_pk_bf16_f32 %0, %1, %2" : "=v"(w1) : "v"(a2), "v"(a3));
        asm("v_cvt_pk_bf16_f32 %0, %1, %2" : "=v"(w2) : "v"(a4), "v"(a5));
        asm("v_cvt_pk_bf16_f32 %0, %1, %2" : "=v"(w3) : "v"(a6), "v"(a7));
        asm("v_permlane32_swap_b32 %0, %1" : "+v"(w0), "+v"(w2));
        asm("v_permlane32_swap_b32 %0, %1" : "+v"(w1), "+v"(w3));
        pf[half * 4 + g] = __builtin_bit_cast(bf16x8, (uint4_t){w0, w1, w2, w3});
      }
    }

    // O^T[d][q] += V^T . P^T
    __builtin_amdgcn_s_setprio(1);
#pragma unroll
    for (int u = 0; u < 8; ++u) {
      int ch = ((u * 2 + lh) ^ swz) * 8;
      bf16x8 a0 = *(const bf16x8*)&Vsm[cur][l31 * 128 + ch];
      bf16x8 a1 = *(const bf16x8*)&Vsm[cur][(32 + l31) * 128 + ch];
      o0 = __builtin_amdgcn_mfma_f32_32x32x16_bf16(a0, pf[u], o0, 0, 0, 0);
      o1 = __builtin_amdgcn_mfma_f32_32x32x16_bf16(a1, pf[u], o1, 0, 0, 0);
    }
    __builtin_amdgcn_s_setprio(0);

    __syncthreads();
    cur ^= 1;
  }

  // write O rows: lane has O^T[d][q] for q=l31, d = (r&3)+8*(r>>2)+4*lh (+32 for o1)
  float inv = 1.0f / lsum;
  unsigned short* op = ob + ((size_t)q * NB + n) * EMB + hh * HD;
#pragma unroll
  for (int g = 0; g < 4; ++g) {
    ushort4_t pk0, pk1;
#pragma unroll
    for (int e = 0; e < 4; ++e) {
      pk0[e] = f2bf(o0[g * 4 + e] * inv);
      pk1[e] = f2bf(o1[g * 4 + e] * inv);
    }
    *(ushort4_t*)(op + g * 8 + lh * 4) = pk0;
    *(ushort4_t*)(op + 32 + g * 8 + lh * 4) = pk1;
  }
}

extern "C" void kernel_launch(void* const* d_in, const int* in_sizes, int n_in,
                              void* d_out, int out_size, void* d_ws, size_t ws_size,
                              hipStream_t stream) {
  const float* x = (const float*)d_in[0];
  const float* wqkv = (const float*)d_in[1];
  const float* bqkv = (const float*)d_in[2];
  const float* wout = (const float*)d_in[3];
  const float* bout = (const float*)d_in[4];

  char* ws = (char*)d_ws;
  unsigned short* xb    = (unsigned short*)(ws);              //  8 MB: x bf16 [4096][1024]
  unsigned short* wqkvb = (unsigned short*)(ws + 8388608);    //  6 MB: Wqkv bf16 [3072][1024]
  unsigned short* woutb = (unsigned short*)(ws + 14680064);   //  2 MB: Wout bf16 [1024][1024]
  unsigned short* qkvb  = (unsigned short*)(ws + 16777216);   // 24 MB: qkv bf16 [4096][3072]
  unsigned short* vtb   = (unsigned short*)(ws + 41943040);   //  8 MB: V^T bf16 [32][64][2048]
  unsigned short* obuf  = (unsigned short*)(ws + 50331648);   //  8 MB: attn out bf16 [4096][1024]

  cvt_all<<<8192, 256, 0, stream>>>(x, wqkv, wout, xb, wqkvb, woutb);

  dim3 g1(32, 24);
  gemm_bf16_nt<true><<<g1, 256, 0, stream>>>(xb, wqkvb, bqkv, qkvb, 4096, 3072, 1024);

  dim3 gt(32, 32);
  transpose_v<<<gt, 256, 0, stream>>>(qkvb, vtb);

  dim3 g2(16, 32);
  flash_attn<<<g2, 256, 0, stream>>>(qkvb, vtb, obuf);

  dim3 g3(32, 8);
  gemm_bf16_nt<false><<<g3, 256, 0, stream>>>(obuf, woutb, bout, d_out, 4096, 1024, 1024);
}